// Round 7
// baseline (374.316 us; speedup 1.0000x reference)
//
#include <hip/hip_runtime.h>

#define N_NODES 50000
#define N_EDGES 800000
#define DIM 64
#define N_LAYERS 3
#define N_GRAPHS 256
#define BN_EPS 1e-5f
#define D3 (DIM * N_LAYERS)
#define N_PART 64
#define NBKT 782          // ceil(50000/64) destination buckets
#define NSUB 8
#define NCTR (NBKT * NSUB)
#define CAP 2048

typedef __attribute__((ext_vector_type(8))) short short8;
typedef __attribute__((ext_vector_type(4))) float floatx4;

// ---------------------------------------------------------- bf16 split utils
__device__ inline unsigned short bf16_rn(float f) {
    unsigned u = __float_as_uint(f);
    u += 0x7FFF + ((u >> 16) & 1);
    return (unsigned short)(u >> 16);
}
__device__ inline float bf16_f(unsigned short b) {
    return __uint_as_float(((unsigned)b) << 16);
}
__device__ inline void split8(float4 a, float4 b, short8* hi, short8* lo) {
    float v[8] = {a.x, a.y, a.z, a.w, b.x, b.y, b.z, b.w};
#pragma unroll
    for (int i = 0; i < 8; i++) {
        unsigned short h = bf16_rn(v[i]);
        (*hi)[i] = (short)h;
        (*lo)[i] = (short)bf16_rn(v[i] - bf16_f(h));
    }
}

// ---------------------------------------------- pass 1: per-(bucket,sub) hist
__global__ __launch_bounds__(256) void pass1_hist(const int* __restrict__ dst,
                                                  int* __restrict__ bcnt) {
    __shared__ int hcnt[NBKT];
    for (int i = threadIdx.x; i < NBKT; i += 256) hcnt[i] = 0;
    __syncthreads();
    int sub = blockIdx.x & (NSUB - 1);
    int base = blockIdx.x * 4096;
#pragma unroll
    for (int k = 0; k < 16; k++) {
        int e = base + k * 256 + threadIdx.x;
        if (e < N_EDGES) atomicAdd(&hcnt[dst[e] >> 6], 1);
    }
    __syncthreads();
    for (int i = threadIdx.x; i < NBKT; i += 256) {
        int c = hcnt[i];
        if (c) atomicAdd(&bcnt[i * NSUB + sub], c);
    }
}

// -------------------------------------- exclusive scan of 6256 counters
__global__ __launch_bounds__(1024) void scan_all(const int* __restrict__ bcnt,
                                                 int* __restrict__ boff) {
    __shared__ int tsum[1024];
    int t = threadIdx.x;
    const int C = (NCTR + 1023) / 1024;   // 7
    int base = t * C;
    int loc[7];
    int s = 0;
    for (int i = 0; i < C; i++) {
        int idx = base + i;
        int v = (idx < NCTR) ? bcnt[idx] : 0;
        loc[i] = s;
        s += v;
    }
    tsum[t] = s;
    __syncthreads();
    for (int off = 1; off < 1024; off <<= 1) {
        int v = (t >= off) ? tsum[t - off] : 0;
        __syncthreads();
        tsum[t] += v;
        __syncthreads();
    }
    int excl = (t > 0) ? tsum[t - 1] : 0;
    for (int i = 0; i < C; i++) {
        int idx = base + i;
        if (idx < NCTR) boff[idx] = excl + loc[i];
    }
    if (t == 0) boff[NCTR] = N_EDGES;
}

// ------------------------- pass 2: partition edges, pack src<<6 | (dst&63)
__global__ __launch_bounds__(256) void pass2_part(const int* __restrict__ src,
                                                  const int* __restrict__ dst,
                                                  const int* __restrict__ boff,
                                                  int* __restrict__ bfill,
                                                  unsigned* __restrict__ ebuf) {
    int sub = blockIdx.x & (NSUB - 1);
    int base = blockIdx.x * 4096;
#pragma unroll
    for (int k = 0; k < 16; k++) {
        int e = base + k * 256 + threadIdx.x;
        if (e < N_EDGES) {
            int d = dst[e];
            int b = d >> 6;
            int pos = boff[b * NSUB + sub] + atomicAdd(&bfill[b * NSUB + sub], 1);
            ebuf[pos] = ((unsigned)src[e] << 6) | (unsigned)(d & 63);
        }
    }
}

// --------- counting-sort each bucket's edges by dst&63 -> per-node CSR + rp
__global__ __launch_bounds__(256) void bucket_sort(const unsigned* __restrict__ ebuf,
                                                   const int* __restrict__ boff,
                                                   int* __restrict__ csr,
                                                   int* __restrict__ rp) {
    __shared__ unsigned ent[CAP];
    __shared__ int cnt[64], basea[64], fill[64];
    int b = blockIdx.x, tid = threadIdx.x;
    int start = boff[b * NSUB], end = boff[b * NSUB + NSUB];
    int T = end - start;
    if (tid < 64) cnt[tid] = 0;
    bool use_lds = (T <= CAP);
    if (use_lds)
        for (int i = tid; i < T; i += 256) ent[i] = ebuf[start + i];
    __syncthreads();
    for (int i = tid; i < T; i += 256) {
        unsigned e = use_lds ? ent[i] : ebuf[start + i];
        atomicAdd(&cnt[e & 63], 1);
    }
    __syncthreads();
    if (tid < 64) {
        int v = cnt[tid], x = v;
#pragma unroll
        for (int off = 1; off < 64; off <<= 1) {
            int y = __shfl_up(x, off);
            if (tid >= off) x += y;
        }
        basea[tid] = x - v;
        fill[tid] = 0;
        rp[b * 64 + tid] = start + x - v;
    }
    __syncthreads();
    for (int i = tid; i < T; i += 256) {
        unsigned e = use_lds ? ent[i] : ebuf[start + i];
        int c = e & 63;
        int pos = basea[c] + atomicAdd(&fill[c], 1);
        csr[start + pos] = (int)(e >> 6);
    }
}

// -------------------------------------------- per-graph node counts (sorted)
__global__ __launch_bounds__(256) void count_graphs(const int* __restrict__ batch,
                                                    int* __restrict__ cntg) {
    int grp = blockIdx.x * 256 + threadIdx.x;
    if (grp >= N_NODES / 8) return;
    int n0 = grp * 8, run = 0, cur = batch[n0];
#pragma unroll
    for (int r = 0; r < 8; r++) {
        int b = batch[n0 + r];
        if (b != cur) { atomicAdd(&cntg[cur], run); run = 0; cur = b; }
        run++;
    }
    atomicAdd(&cntg[cur], run);
}

// -------- gather + prev-layer BN affine: z[i] = sc*(h[i]+sum h[j]) + (1+deg)*sh
__global__ __launch_bounds__(256) void gather_kernel(const float* __restrict__ h,
                                                     float* __restrict__ z,
                                                     const int* __restrict__ rp,
                                                     const int* __restrict__ csr,
                                                     const float* __restrict__ ss) {
    int node = blockIdx.x * 4 + (threadIdx.x >> 6);
    if (node >= N_NODES) return;
    int lane = threadIdx.x & 63;
    float acc = h[(size_t)node * DIM + lane];
    int e = rp[node], end = rp[node + 1];
    float degf = 1.f + (float)(end - e);
    for (; e + 8 <= end; e += 8) {
        int s0 = csr[e],     s1 = csr[e + 1], s2 = csr[e + 2], s3 = csr[e + 3];
        int s4 = csr[e + 4], s5 = csr[e + 5], s6 = csr[e + 6], s7 = csr[e + 7];
        float v0 = h[(size_t)s0 * DIM + lane];
        float v1 = h[(size_t)s1 * DIM + lane];
        float v2 = h[(size_t)s2 * DIM + lane];
        float v3 = h[(size_t)s3 * DIM + lane];
        float v4 = h[(size_t)s4 * DIM + lane];
        float v5 = h[(size_t)s5 * DIM + lane];
        float v6 = h[(size_t)s6 * DIM + lane];
        float v7 = h[(size_t)s7 * DIM + lane];
        acc += ((v0 + v1) + (v2 + v3)) + ((v4 + v5) + (v6 + v7));
    }
    for (; e < end; e++) acc += h[(size_t)csr[e] * DIM + lane];
    if (ss) acc = fmaf(acc, ss[lane], degf * ss[DIM + lane]);
    z[(size_t)node * DIM + lane] = acc;
}

// --------------- pack W1/W2 into MFMA B-operand fragments, split bf16 hi/lo
__global__ __launch_bounds__(256) void prep_weights(const float* __restrict__ W1,
                                                    const float* __restrict__ W2,
                                                    unsigned short* __restrict__ wf) {
    int idx = blockIdx.x * 256 + threadIdx.x;
    if (idx >= N_LAYERS * 2 * 4096) return;
    int j    = idx & 7;
    int lane = (idx >> 3) & 63;
    int ks   = (idx >> 9) & 1;
    int nt   = (idx >> 10) & 3;
    int gemm = (idx >> 12) & 1;
    int layer = idx >> 13;
    int n = nt * 16 + (lane & 15);
    int k = ks * 32 + (lane >> 4) * 8 + j;
    const float* W = (gemm ? W2 : W1) + (size_t)layer * DIM * DIM;
    float w = W[k * DIM + n];
    unsigned short hi = bf16_rn(w);
    unsigned short lo = bf16_rn(w - bf16_f(hi));
    size_t base = ((size_t)layer * 2 + gemm) * 8192;
    int f = nt * 2 + ks;
    wf[base + f * 512 + lane * 8 + j]        = hi;
    wf[base + 4096 + f * 512 + lane * 8 + j] = lo;
}

// ------- MFMA MLP: raw z' = relu(relu(zW1+B1)W2+B2) + BN partials + raw pool
#define HS_STRIDE 68
__global__ __launch_bounds__(256) void mlp_mfma(float* __restrict__ z,
    const unsigned short* __restrict__ wfL,
    const float* __restrict__ B1, const float* __restrict__ B2,
    float* __restrict__ sums_part, float* __restrict__ praw,
    const int* __restrict__ batch, int write_z) {
    __shared__ float sH[4][16 * HS_STRIDE];
    __shared__ float sSum[2 * DIM];
    __shared__ int   sBatch[64];

    int tid = threadIdx.x, wave = tid >> 6, lane = tid & 63;
    int blk0 = blockIdx.x * 64;
    if (tid < 2 * DIM) sSum[tid] = 0.f;
    if (tid < 64) sBatch[tid] = (blk0 + tid < N_NODES) ? batch[blk0 + tid] : -1;
    __syncthreads();

    int m = lane & 15, quad = lane >> 4;
    int row0 = blk0 + wave * 16;
    int grow = row0 + m;
    int ar = grow < N_NODES ? grow : N_NODES - 1;

    const float4* zr = (const float4*)(z + (size_t)ar * DIM);
    float4 a0 = zr[quad * 2],     a1 = zr[quad * 2 + 1];
    float4 a2 = zr[8 + quad * 2], a3 = zr[8 + quad * 2 + 1];
    short8 Ah0, Al0, Ah1, Al1;
    split8(a0, a1, &Ah0, &Al0);
    split8(a2, a3, &Ah1, &Al1);

    floatx4 acc[4];
#pragma unroll
    for (int nt = 0; nt < 4; nt++) acc[nt] = (floatx4){0.f, 0.f, 0.f, 0.f};
#pragma unroll
    for (int nt = 0; nt < 4; nt++) {
#pragma unroll
        for (int ks = 0; ks < 2; ks++) {
            const short8 Bh = *(const short8*)(wfL + (nt * 2 + ks) * 512 + lane * 8);
            const short8 Bl = *(const short8*)(wfL + 4096 + (nt * 2 + ks) * 512 + lane * 8);
            short8 Ahf = ks ? Ah1 : Ah0;
            short8 Alf = ks ? Al1 : Al0;
            acc[nt] = __builtin_amdgcn_mfma_f32_16x16x32_bf16(Ahf, Bh, acc[nt], 0, 0, 0);
            acc[nt] = __builtin_amdgcn_mfma_f32_16x16x32_bf16(Ahf, Bl, acc[nt], 0, 0, 0);
            acc[nt] = __builtin_amdgcn_mfma_f32_16x16x32_bf16(Alf, Bh, acc[nt], 0, 0, 0);
        }
    }

    float* Hs = sH[wave];
#pragma unroll
    for (int nt = 0; nt < 4; nt++) {
        int col = nt * 16 + m;
        float b = B1[col];
#pragma unroll
        for (int r = 0; r < 4; r++) {
            int lr = quad * 4 + r;
            Hs[lr * HS_STRIDE + col] = fmaxf(acc[nt][r] + b, 0.f);
        }
    }
    float4 h0 = *(const float4*)&Hs[m * HS_STRIDE + quad * 8];
    float4 h1 = *(const float4*)&Hs[m * HS_STRIDE + quad * 8 + 4];
    float4 h2 = *(const float4*)&Hs[m * HS_STRIDE + 32 + quad * 8];
    float4 h3 = *(const float4*)&Hs[m * HS_STRIDE + 32 + quad * 8 + 4];
    short8 Hh0, Hl0, Hh1, Hl1;
    split8(h0, h1, &Hh0, &Hl0);
    split8(h2, h3, &Hh1, &Hl1);

    floatx4 acc2[4];
#pragma unroll
    for (int nt = 0; nt < 4; nt++) acc2[nt] = (floatx4){0.f, 0.f, 0.f, 0.f};
    const unsigned short* wg2 = wfL + 8192;
#pragma unroll
    for (int nt = 0; nt < 4; nt++) {
#pragma unroll
        for (int ks = 0; ks < 2; ks++) {
            const short8 Bh = *(const short8*)(wg2 + (nt * 2 + ks) * 512 + lane * 8);
            const short8 Bl = *(const short8*)(wg2 + 4096 + (nt * 2 + ks) * 512 + lane * 8);
            short8 Ahf = ks ? Hh1 : Hh0;
            short8 Alf = ks ? Hl1 : Hl0;
            acc2[nt] = __builtin_amdgcn_mfma_f32_16x16x32_bf16(Ahf, Bh, acc2[nt], 0, 0, 0);
            acc2[nt] = __builtin_amdgcn_mfma_f32_16x16x32_bf16(Ahf, Bl, acc2[nt], 0, 0, 0);
            acc2[nt] = __builtin_amdgcn_mfma_f32_16x16x32_bf16(Alf, Bh, acc2[nt], 0, 0, 0);
        }
    }

    // ---- epilogue: raw z write + BN partials + per-graph raw pooling
    int widx = wave * 16;
    int gfirst = sBatch[widx], glast = sBatch[widx + 15];
    bool uni = (gfirst == glast) && (gfirst >= 0);
#pragma unroll
    for (int nt = 0; nt < 4; nt++) {
        int col = nt * 16 + m;
        float b = B2[col];
        float vv[4];
        float s = 0.f, s2 = 0.f;
#pragma unroll
        for (int r = 0; r < 4; r++) {
            int gr = row0 + quad * 4 + r;
            float v = fmaxf(acc2[nt][r] + b, 0.f);
            if (gr < N_NODES) {
                if (write_z) z[(size_t)gr * DIM + col] = v;
                s += v;
                s2 = fmaf(v, v, s2);
                vv[r] = v;
            } else {
                vv[r] = 0.f;
            }
        }
        float sf = s, s2f = s2;
        sf  += __shfl_xor(sf, 16);  sf  += __shfl_xor(sf, 32);
        s2f += __shfl_xor(s2f, 16); s2f += __shfl_xor(s2f, 32);
        if (quad == 0) {
            atomicAdd(&sSum[col], sf);
            atomicAdd(&sSum[DIM + col], s2f);
            if (uni) atomicAdd(&praw[(size_t)gfirst * DIM + col], sf);
        }
        if (!uni) {
            int cur = -1; float run = 0.f;
#pragma unroll
            for (int r = 0; r < 4; r++) {
                int g = sBatch[widx + quad * 4 + r];
                if (g != cur) {
                    if (cur >= 0 && run != 0.f)
                        atomicAdd(&praw[(size_t)cur * DIM + col], run);
                    run = 0.f; cur = g;
                }
                run += vv[r];
            }
            if (cur >= 0 && run != 0.f)
                atomicAdd(&praw[(size_t)cur * DIM + col], run);
        }
    }
    __syncthreads();
    if (tid < 2 * DIM)
        atomicAdd(&sums_part[(size_t)(blockIdx.x & (N_PART - 1)) * 2 * DIM + tid], sSum[tid]);
}

// --------------------------------------------- BN scale/shift from partials
__global__ void finalize_stats(const float* __restrict__ sp,
                               const float* __restrict__ gamma,
                               const float* __restrict__ beta,
                               float* __restrict__ ss) {
    int c = threadIdx.x;
    float s = 0.f, q = 0.f;
    for (int p = 0; p < N_PART; p++) {
        s += sp[p * 2 * DIM + c];
        q += sp[p * 2 * DIM + DIM + c];
    }
    const float inv_n = 1.0f / (float)N_NODES;
    float mu  = s * inv_n;
    float var = q * inv_n - mu * mu;
    float sc  = gamma[c] / sqrtf(var + BN_EPS);
    ss[c]       = sc;
    ss[DIM + c] = beta[c] - mu * sc;
}

// ------------------- pooled[g][L*64+c] = sc*praw + cnt_g*sh
__global__ __launch_bounds__(256) void assemble_pooled(const float* __restrict__ praw,
                                                       const float* __restrict__ ssAll,
                                                       const int* __restrict__ cntg,
                                                       float* __restrict__ pooled) {
    int idx = blockIdx.x * 256 + threadIdx.x;
    if (idx >= N_GRAPHS * D3) return;
    int g = idx / D3, j = idx - g * D3, L = j >> 6, c = j & 63;
    float sc = ssAll[L * 2 * DIM + c], sh = ssAll[L * 2 * DIM + DIM + c];
    pooled[idx] = fmaf(sc, praw[((size_t)L * N_GRAPHS + g) * DIM + c],
                       (float)cntg[g] * sh);
}

// ------------------------------------------------ final 2-layer MLP on pooled
__global__ __launch_bounds__(192) void final_mlp(const float* __restrict__ pooled,
    const float* __restrict__ PW1, const float* __restrict__ PB1,
    const float* __restrict__ PW2, const float* __restrict__ PB2,
    float* __restrict__ out) {
    __shared__ float row[D3];
    __shared__ float hid[D3];
    int g = blockIdx.x, j = threadIdx.x;
    row[j] = pooled[(size_t)g * D3 + j];
    __syncthreads();
    float acc = PB1[j];
    for (int k = 0; k < D3; k++) acc = fmaf(row[k], PW1[k * D3 + j], acc);
    hid[j] = fmaxf(acc, 0.f);
    __syncthreads();
    float acc2 = PB2[j];
    for (int k = 0; k < D3; k++) acc2 = fmaf(hid[k], PW2[k * D3 + j], acc2);
    out[(size_t)g * D3 + j] = acc2;
}

extern "C" void kernel_launch(void* const* d_in, const int* in_sizes, int n_in,
                              void* d_out, int out_size, void* d_ws, size_t ws_size,
                              hipStream_t stream) {
    const float* x     = (const float*)d_in[0];
    const int*   ei    = (const int*)d_in[1];
    const int*   batch = (const int*)d_in[2];
    const float* W1    = (const float*)d_in[3];
    const float* B1    = (const float*)d_in[4];
    const float* W2    = (const float*)d_in[5];
    const float* B2    = (const float*)d_in[6];
    const float* gamma = (const float*)d_in[7];
    const float* beta  = (const float*)d_in[8];
    const float* PW1   = (const float*)d_in[9];
    const float* PB1   = (const float*)d_in[10];
    const float* PW2   = (const float*)d_in[11];
    const float* PB2   = (const float*)d_in[12];
    float* out = (float*)d_out;

    // -------- workspace layout (ebuf aliases bufB: dead before layer 1)
    float*    bufA  = (float*)d_ws;                              // 3,200,000 f
    float*    bufB  = bufA + (size_t)N_NODES * DIM;              // 3,200,000 f
    unsigned* ebuf  = (unsigned*)bufB;                           // alias
    int*      csr   = (int*)(bufB + (size_t)N_NODES * DIM);      // 800,000 i
    int*      rp    = csr + N_EDGES;                             // 50,056 i
    int*      boff  = rp + 50056;                                // 6,264 i
    unsigned short* wfrag = (unsigned short*)(boff + 6264);      // 49,152 u16
    float*    ssbuf = (float*)(wfrag + 49152);                   // 384 f
    float*    pooled = ssbuf + N_LAYERS * 2 * DIM;               // 49,152 f
    // ---- zeroed region
    int*      bcnt  = (int*)(pooled + N_GRAPHS * D3);            // 6,256 i
    int*      bfill = bcnt + NCTR;                               // 6,256 i
    int*      cntg  = bfill + NCTR;                              // 256 i
    float*    sums_part = (float*)(cntg + N_GRAPHS);             // 24,576 f
    float*    praw  = sums_part + N_LAYERS * N_PART * 2 * DIM;   // 49,152 f

    const int* src = ei;
    const int* dst = ei + N_EDGES;

    const size_t zero_bytes =
        (size_t)(2 * NCTR + N_GRAPHS) * sizeof(int) +
        (size_t)(N_LAYERS * N_PART * 2 * DIM + N_LAYERS * N_GRAPHS * DIM) * sizeof(float);
    hipMemsetAsync(bcnt, 0, zero_bytes, stream);

    // -------- CSR build + weight prep + graph counts
    const int PB = (N_EDGES + 4095) / 4096;       // 196
    pass1_hist<<<PB, 256, 0, stream>>>(dst, bcnt);
    scan_all<<<1, 1024, 0, stream>>>(bcnt, boff);
    pass2_part<<<PB, 256, 0, stream>>>(src, dst, boff, bfill, ebuf);
    bucket_sort<<<NBKT, 256, 0, stream>>>(ebuf, boff, csr, rp);
    prep_weights<<<(N_LAYERS * 2 * 4096 + 255) / 256, 256, 0, stream>>>(W1, W2, wfrag);
    count_graphs<<<(N_NODES / 8 + 255) / 256, 256, 0, stream>>>(batch, cntg);

    // -------- layers: gather(+affine) -> mlp(raw z + stats + raw pool)
    const float* P = x;
    float* Q = bufA;
    const float* ssPrev = nullptr;
    const int MB = (N_NODES + 63) / 64;   // 782
    for (int L = 0; L < N_LAYERS; ++L) {
        int write_z = (L < N_LAYERS - 1);
        gather_kernel<<<(N_NODES + 3) / 4, 256, 0, stream>>>(P, Q, rp, csr, ssPrev);
        mlp_mfma<<<MB, 256, 0, stream>>>(
            Q, wfrag + (size_t)L * 2 * 8192, B1 + (size_t)L * DIM, B2 + (size_t)L * DIM,
            sums_part + (size_t)L * N_PART * 2 * DIM,
            praw + (size_t)L * N_GRAPHS * DIM, batch, write_z);
        finalize_stats<<<1, DIM, 0, stream>>>(sums_part + (size_t)L * N_PART * 2 * DIM,
                                              gamma + (size_t)L * DIM,
                                              beta + (size_t)L * DIM,
                                              ssbuf + (size_t)L * 2 * DIM);
        ssPrev = ssbuf + (size_t)L * 2 * DIM;
        P = Q;
        Q = (Q == bufA) ? bufB : bufA;
    }

    assemble_pooled<<<(N_GRAPHS * D3 + 255) / 256, 256, 0, stream>>>(praw, ssbuf, cntg, pooled);
    final_mlp<<<N_GRAPHS, 192, 0, stream>>>(pooled, PW1, PB1, PW2, PB2, out);
}